// Round 8
// baseline (3435.682 us; speedup 1.0000x reference)
//
#include <hip/hip_runtime.h>
#include <stdint.h>

// UniLSTM: B=64, T=512, E=1024, H=1024.
// Phase 0: f32->f16 converts + bias sum.
// Phase 1: xprojT[T][64][4096] = (x @ W_ih^T + bsum), f16, time-major.
// Phase 2: persistent recurrence, 256 WGs x 256 thr = 4 groups x 64 unit-slices.
//   R8 = R5 byte-identical + ONE change: 64MiB hbuf pre-warm memset after the
//   GEMM. Fresh-slot h exchange with flags + CACHED gather (L2 dedup per XCD),
//   but now producer stores are LLC HITS (no HBM fetch-on-write merge on the
//   drained critical path) and consumer fills are LLC hits. Pure A/B on the
//   R5 store-miss theory.

typedef _Float16 half8 __attribute__((ext_vector_type(8)));
typedef _Float16 half4_ __attribute__((ext_vector_type(4)));
typedef float f32x4 __attribute__((ext_vector_type(4)));
typedef unsigned int u32x4 __attribute__((ext_vector_type(4)));

#define T_SEQ 512

// ---------------- converts ----------------
__global__ void k_f32_to_f16(const float* __restrict__ s, _Float16* __restrict__ d, int n4) {
  int i = blockIdx.x * blockDim.x + threadIdx.x;
  if (i >= n4) return;
  f32x4 v = ((const f32x4*)s)[i];
  half4_ h;
  h.x = (_Float16)v.x; h.y = (_Float16)v.y; h.z = (_Float16)v.z; h.w = (_Float16)v.w;
  ((half4_*)d)[i] = h;
}

__global__ void k_bias_sum(const float* __restrict__ a, const float* __restrict__ b,
                           float* __restrict__ o) {
  int i = blockIdx.x * blockDim.x + threadIdx.x;
  if (i < 4096) o[i] = a[i] + b[i];
}

// ---------------- phase 1: input projection GEMM ----------------
// logical C[M=32768, N=4096] = X[M,1024] @ W[N,1024]^T + bsum[N], stored TIME-MAJOR:
// row = b*512+t -> written at C[(t*64 + b)*4096 + col]
__global__ __launch_bounds__(256, 2) void k_gemm_xproj(
    const _Float16* __restrict__ X, const _Float16* __restrict__ W,
    const float* __restrict__ bsum, _Float16* __restrict__ C) {
  __shared__ _Float16 As[128 * 64];
  __shared__ _Float16 Bs[128 * 64];
  const int bid = blockIdx.x;
  const int ntile = bid & 31, mtile = bid >> 5;
  const int tid = threadIdx.x;
  const int wave = tid >> 6, lane = tid & 63;
  const int wr = wave >> 1, wc = wave & 1;
  const int R0 = lane >> 3, cg = lane & 7;

  f32x4 acc[4][4];
#pragma unroll
  for (int m = 0; m < 4; m++)
#pragma unroll
    for (int n = 0; n < 4; n++) acc[m][n] = (f32x4){0.f, 0.f, 0.f, 0.f};

  for (int k0 = 0; k0 < 1024; k0 += 64) {
#pragma unroll
    for (int i = 0; i < 4; i++) {
      const int rr = (wave * 4 + i) * 8 + R0;
      const _Float16* ga = X + (size_t)(mtile * 128 + rr) * 1024 + k0 + ((cg ^ (rr & 7)) * 8);
      const _Float16* gb = W + (size_t)(ntile * 128 + rr) * 1024 + k0 + ((cg ^ (rr & 7)) * 8);
      __builtin_amdgcn_global_load_lds(
          (const __attribute__((address_space(1))) void*)ga,
          (__attribute__((address_space(3))) void*)((char*)As + (wave * 4 + i) * 1024), 16, 0, 0);
      __builtin_amdgcn_global_load_lds(
          (const __attribute__((address_space(1))) void*)gb,
          (__attribute__((address_space(3))) void*)((char*)Bs + (wave * 4 + i) * 1024), 16, 0, 0);
    }
    asm volatile("s_waitcnt vmcnt(0)" ::: "memory");
    __syncthreads();
#pragma unroll
    for (int kk = 0; kk < 2; kk++) {
      half8 af[4], bf[4];
#pragma unroll
      for (int m = 0; m < 4; m++) {
        int r = wr * 64 + m * 16 + (lane & 15);
        af[m] = *(const half8*)((const char*)As + r * 128 +
                                (((kk * 4 + (lane >> 4)) ^ (r & 7)) << 4));
      }
#pragma unroll
      for (int n = 0; n < 4; n++) {
        int r = wc * 64 + n * 16 + (lane & 15);
        bf[n] = *(const half8*)((const char*)Bs + r * 128 +
                                (((kk * 4 + (lane >> 4)) ^ (r & 7)) << 4));
      }
#pragma unroll
      for (int m = 0; m < 4; m++)
#pragma unroll
        for (int n = 0; n < 4; n++)
          acc[m][n] = __builtin_amdgcn_mfma_f32_16x16x32_f16(af[m], bf[n], acc[m][n], 0, 0, 0);
    }
    __syncthreads();
  }
#pragma unroll
  for (int n = 0; n < 4; n++) {
    int col = ntile * 128 + wc * 64 + n * 16 + (lane & 15);
    float bs = bsum[col];
#pragma unroll
    for (int m = 0; m < 4; m++)
#pragma unroll
      for (int q = 0; q < 4; q++) {
        int row = mtile * 128 + wr * 64 + m * 16 + (lane >> 4) * 4 + q;  // = b*512 + t
        int bb = row >> 9, tt = row & 511;
        C[((size_t)tt * 64 + bb) * 4096 + col] = (_Float16)(acc[m][n][q] + bs);
      }
  }
}

// ---------------- phase 2: recurrence ----------------
// WG (g, s): XCD-swizzled: g=(bid&7)>>1, s=(bid&1)*32+(bid>>3) -> all 32 WGs on
// one XCD share (g, s-half): group h-slice + xprojT slab L2-dedup'd per XCD.
// Wave w = gate w; MFMA col n = unit s*16+n -> W_hh row 1024*w + s*16 + n.
__global__ __launch_bounds__(256, 1) void k_lstm_rec(
    const _Float16* __restrict__ Whh,     // [4096][1024] f16
    const _Float16* __restrict__ xprojT,  // [512][64][4096] f16 time-major
    const int* __restrict__ seqlen,       // [64]
    _Float16* __restrict__ hbuf,          // [512][64][1024] f16, slot t = h_t (PREWARMED)
    unsigned* __restrict__ flags,         // [512][4][64][4] u32, zeroed per launch
    float* __restrict__ out) {            // [64][1024] f32
  __shared__ _Float16 h_lds[16 * 1024];  // 32 KB, XOR-swizzled 16B chunks
  __shared__ float gates[64 * 17];       // transposed [col][row], pad 17

  const int bid = blockIdx.x;
  const int x8 = bid & 7;                    // XCD (perf heuristic only)
  const int g = x8 >> 1;                     // batch group 0..3
  const int s = (x8 & 1) * 32 + (bid >> 3);  // unit slice 0..63
  const int tid = threadIdx.x;
  const int wave = tid >> 6, lane = tid & 63;

  for (int i = tid; i < 4096; i += 256) ((uint64_t*)h_lds)[i] = 0ull;  // h_0 = 0

  // W_hh B-fragments, register-resident (mapping validated R2/R5/R6)
  half8 wfrag[32];
  {
    const _Float16* wp =
        Whh + (size_t)(1024 * wave + s * 16 + (lane & 15)) * 1024 + (lane >> 4) * 8;
#pragma unroll
    for (int kk = 0; kk < 32; kk++) wfrag[kk] = *(const half8*)(wp + kk * 32);
  }

  int Lg = 1;
  for (int b = 0; b < 16; b++) {
    int L = seqlen[g * 16 + b];
    Lg = L > Lg ? L : Lg;
  }
  const int be = tid >> 4, ue = tid & 15;  // elementwise cell (batch row, unit)
  const int mylen = seqlen[g * 16 + be];
  float c_state = 0.f;

  const int rowbase = (lane & 15) * 2048;   // A-frag row byte base
  const int xorm = ((lane & 15) & 7) << 4;  // A-frag XOR swizzle

  __syncthreads();  // h_lds zeros visible for t=0

  for (int t = 0; t < Lg; t++) {
    // xp loads (independent of h), issued before the poll
    float xp[4];
#pragma unroll
    for (int q = 0; q < 4; q++) {
      int bm = (lane >> 4) * 4 + q;
      xp[q] = (float)xprojT[((size_t)t * 64 + g * 16 + bm) * 4096 + 1024 * wave + s * 16 +
                            (lane & 15)];
    }

    if (t > 0) {
      // poll 256 per-wave flags of (t, g): one dwordx4 per lane, LLC-bypass
      const unsigned* fl = flags + (((size_t)t * 4 + g) << 8) + lane * 4;
      u32x4 fv;
      for (;;) {
        asm volatile("global_load_dwordx4 %0, %1, off sc0 sc1"
                     : "=v"(fv) : "v"(fl) : "memory");
        asm volatile("s_waitcnt vmcnt(0)" ::: "memory");
        bool ok = fv.x != 0u && fv.y != 0u && fv.z != 0u && fv.w != 0u;
        if (__all(ok)) break;
      }
      // gather h_t: fresh-slot addresses -> plain CACHED loads. Fill-after-flag
      // guarantees freshness; L2 dedups across the 32 WGs of this XCD.
      const u32x4* src = (const u32x4*)(hbuf + (size_t)t * 65536 + (size_t)g * 16384);
      u32x4 hv[8];
#pragma unroll
      for (int i = 0; i < 8; i++) hv[i] = src[tid + (i << 8)];
#pragma unroll
      for (int i = 0; i < 8; i++) {
        int ch = tid + (i << 8);
        int b = ch >> 7, j = ch & 127;
        *(u32x4*)((char*)h_lds + b * 2048 + ((j ^ (b & 7)) << 4)) = hv[i];
      }
    }
    __syncthreads();  // (A) h_lds ready; also WAR-protects gates

    // gates: M=16 x N=16, K=1024 -> 32 MFMAs in 4 accumulator chains
    f32x4 a0 = (f32x4){0.f, 0.f, 0.f, 0.f};
    f32x4 a1 = (f32x4){0.f, 0.f, 0.f, 0.f};
    f32x4 a2 = (f32x4){0.f, 0.f, 0.f, 0.f};
    f32x4 a3 = (f32x4){0.f, 0.f, 0.f, 0.f};
    const char* lb = (const char*)h_lds + rowbase;
#pragma unroll
    for (int kk = 0; kk < 32; kk += 4) {
      half8 f0 = *(const half8*)(lb + ((((kk + 0) * 4 + (lane >> 4)) << 4) ^ xorm));
      half8 f1 = *(const half8*)(lb + ((((kk + 1) * 4 + (lane >> 4)) << 4) ^ xorm));
      half8 f2 = *(const half8*)(lb + ((((kk + 2) * 4 + (lane >> 4)) << 4) ^ xorm));
      half8 f3 = *(const half8*)(lb + ((((kk + 3) * 4 + (lane >> 4)) << 4) ^ xorm));
      a0 = __builtin_amdgcn_mfma_f32_16x16x32_f16(f0, wfrag[kk + 0], a0, 0, 0, 0);
      a1 = __builtin_amdgcn_mfma_f32_16x16x32_f16(f1, wfrag[kk + 1], a1, 0, 0, 0);
      a2 = __builtin_amdgcn_mfma_f32_16x16x32_f16(f2, wfrag[kk + 2], a2, 0, 0, 0);
      a3 = __builtin_amdgcn_mfma_f32_16x16x32_f16(f3, wfrag[kk + 3], a3, 0, 0, 0);
    }
    {
      f32x4 gv4;
#pragma unroll
      for (int q = 0; q < 4; q++) gv4[q] = (a0[q] + a1[q]) + (a2[q] + a3[q]) + xp[q];
      *(f32x4*)&gates[(wave * 16 + (lane & 15)) * 17 + (lane >> 4) * 4] = gv4;
    }
    __syncthreads();  // (B) gates ready

    // elementwise: thread owns (be, ue)
    float iv = gates[(0 + ue) * 17 + be];
    float fv = gates[(16 + ue) * 17 + be];
    float gv = gates[(32 + ue) * 17 + be];
    float ov = gates[(48 + ue) * 17 + be];
    iv = 1.f / (1.f + __expf(-iv));
    fv = 1.f / (1.f + __expf(-fv));
    gv = 1.f - 2.f / (1.f + __expf(2.f * gv));
    ov = 1.f / (1.f + __expf(-ov));
    c_state = fv * c_state + iv * gv;
    float tc = 1.f - 2.f / (1.f + __expf(2.f * c_state));
    float hv = ov * tc;
    if (t + 1 == mylen) out[(size_t)(g * 16 + be) * 1024 + s * 16 + ue] = hv;

    if (t + 1 < Lg) {
      _Float16 hf = (_Float16)hv;
      unsigned short hb;
      __builtin_memcpy(&hb, &hf, 2);
      // agent-scope store; line is LLC-resident (prewarm) -> fast hit-ack
      __hip_atomic_store((unsigned short*)hbuf + (size_t)(t + 1) * 65536 +
                             (size_t)(g * 16 + be) * 1024 + s * 16 + ue,
                         hb, __ATOMIC_RELAXED, __HIP_MEMORY_SCOPE_AGENT);
      asm volatile("s_waitcnt vmcnt(0)" ::: "memory");  // per-wave store-ack drain
      if (lane == 0)
        __hip_atomic_store(&flags[(((size_t)(t + 1) * 4 + g) << 8) + s * 4 + wave], 1u,
                           __ATOMIC_RELAXED, __HIP_MEMORY_SCOPE_AGENT);
    }
  }
}

// ---------------- launch ----------------
extern "C" void kernel_launch(void* const* d_in, const int* in_sizes, int n_in, void* d_out,
                              int out_size, void* d_ws, size_t ws_size, hipStream_t stream) {
  const float* emb = (const float*)d_in[0];   // [64,512,1024]
  const int* slen = (const int*)d_in[1];      // [64]
  const float* Wih = (const float*)d_in[2];   // [4096,1024]
  const float* Whh = (const float*)d_in[3];   // [4096,1024]
  const float* bih = (const float*)d_in[4];   // [4096]
  const float* bhh = (const float*)d_in[5];   // [4096]
  float* out = (float*)d_out;

  char* ws = (char*)d_ws;
  _Float16* xprojT = (_Float16*)(ws + 0);        // 268,435,456 B [512][64][4096]
  _Float16* xf = (_Float16*)(ws + 268435456);    //  67,108,864 B (dead after GEMM)
  _Float16* hbuf = (_Float16*)(ws + 268435456);  //  67,108,864 B [512][64][1024] (aliases xf)
  _Float16* wihf = (_Float16*)(ws + 335544320);  //   8,388,608 B
  _Float16* whhf = (_Float16*)(ws + 343932928);  //   8,388,608 B
  float* bsum = (float*)(ws + 352321536);        //      16,384 B
  unsigned* flags = (unsigned*)(ws + 352337920); //   2,097,152 B [512][4][64][4]
  // total ws use: 354,435,072 B

  hipMemsetAsync(flags, 0, 2097152, stream);
  k_f32_to_f16<<<(8388608 + 255) / 256, 256, 0, stream>>>(emb, xf, 8388608);
  k_f32_to_f16<<<(1048576 + 255) / 256, 256, 0, stream>>>(Wih, wihf, 1048576);
  k_f32_to_f16<<<(1048576 + 255) / 256, 256, 0, stream>>>(Whh, whhf, 1048576);
  k_bias_sum<<<16, 256, 0, stream>>>(bih, bhh, bsum);
  k_gemm_xproj<<<8192, 256, 0, stream>>>(xf, wihf, bsum, xprojT);
  // R8's single change: pre-warm ALL hbuf lines into the LLC (64 MiB < 256 MiB)
  // AFTER the GEMM consumed xf. Producer stores become LLC hits; consumer
  // fills read LLC-hit fresh data. Also zeroes stale h from prior replays.
  hipMemsetAsync(hbuf, 0, 67108864, stream);
  k_lstm_rec<<<256, 256, 0, stream>>>(whhf, xprojT, slen, hbuf, flags, out);
}

// Round 9
// 3093.530 us; speedup vs baseline: 1.1106x; 1.1106x over previous
//
#include <hip/hip_runtime.h>
#include <stdint.h>

// UniLSTM: B=64, T=512, E=1024, H=1024.
// Phase 0: f32->f16 converts + bias sum.
// Phase 1: xprojT[T][64][4096] = (x @ W_ih^T + bsum), f16, time-major.
// Phase 2: persistent recurrence, 128 WGs x 512 thr = 4 groups x 32 unit-slices.
//   R9 = R6's tagged ping-pong exchange (data+readiness in one word, ONE LLC
//   round trip, no flags/drains/extra barriers) at HALF the WG count:
//   halves the bypass poll traffic and consumers-per-sector. Single poll loop,
//   single barrier pair (NOT R7's serializing split-K). Wave->(gate,half)
//   mapping and gates[.][17] layout as validated in R7.

typedef _Float16 half8 __attribute__((ext_vector_type(8)));
typedef _Float16 half4_ __attribute__((ext_vector_type(4)));
typedef float f32x4 __attribute__((ext_vector_type(4)));
typedef unsigned int u32x4 __attribute__((ext_vector_type(4)));

// ---------------- converts ----------------
__global__ void k_f32_to_f16(const float* __restrict__ s, _Float16* __restrict__ d, int n4) {
  int i = blockIdx.x * blockDim.x + threadIdx.x;
  if (i >= n4) return;
  f32x4 v = ((const f32x4*)s)[i];
  half4_ h;
  h.x = (_Float16)v.x; h.y = (_Float16)v.y; h.z = (_Float16)v.z; h.w = (_Float16)v.w;
  ((half4_*)d)[i] = h;
}

__global__ void k_bias_sum(const float* __restrict__ a, const float* __restrict__ b,
                           float* __restrict__ o) {
  int i = blockIdx.x * blockDim.x + threadIdx.x;
  if (i < 4096) o[i] = a[i] + b[i];
}

// ---------------- phase 1: input projection GEMM ----------------
// logical C[M=32768, N=4096] = X[M,1024] @ W[N,1024]^T + bsum[N], stored TIME-MAJOR:
// row = b*512+t -> written at C[(t*64 + b)*4096 + col]
__global__ __launch_bounds__(256, 2) void k_gemm_xproj(
    const _Float16* __restrict__ X, const _Float16* __restrict__ W,
    const float* __restrict__ bsum, _Float16* __restrict__ C) {
  __shared__ _Float16 As[128 * 64];
  __shared__ _Float16 Bs[128 * 64];
  const int bid = blockIdx.x;
  const int ntile = bid & 31, mtile = bid >> 5;
  const int tid = threadIdx.x;
  const int wave = tid >> 6, lane = tid & 63;
  const int wr = wave >> 1, wc = wave & 1;
  const int R0 = lane >> 3, cg = lane & 7;

  f32x4 acc[4][4];
#pragma unroll
  for (int m = 0; m < 4; m++)
#pragma unroll
    for (int n = 0; n < 4; n++) acc[m][n] = (f32x4){0.f, 0.f, 0.f, 0.f};

  for (int k0 = 0; k0 < 1024; k0 += 64) {
#pragma unroll
    for (int i = 0; i < 4; i++) {
      const int rr = (wave * 4 + i) * 8 + R0;
      const _Float16* ga = X + (size_t)(mtile * 128 + rr) * 1024 + k0 + ((cg ^ (rr & 7)) * 8);
      const _Float16* gb = W + (size_t)(ntile * 128 + rr) * 1024 + k0 + ((cg ^ (rr & 7)) * 8);
      __builtin_amdgcn_global_load_lds(
          (const __attribute__((address_space(1))) void*)ga,
          (__attribute__((address_space(3))) void*)((char*)As + (wave * 4 + i) * 1024), 16, 0, 0);
      __builtin_amdgcn_global_load_lds(
          (const __attribute__((address_space(1))) void*)gb,
          (__attribute__((address_space(3))) void*)((char*)Bs + (wave * 4 + i) * 1024), 16, 0, 0);
    }
    asm volatile("s_waitcnt vmcnt(0)" ::: "memory");
    __syncthreads();
#pragma unroll
    for (int kk = 0; kk < 2; kk++) {
      half8 af[4], bf[4];
#pragma unroll
      for (int m = 0; m < 4; m++) {
        int r = wr * 64 + m * 16 + (lane & 15);
        af[m] = *(const half8*)((const char*)As + r * 128 +
                                (((kk * 4 + (lane >> 4)) ^ (r & 7)) << 4));
      }
#pragma unroll
      for (int n = 0; n < 4; n++) {
        int r = wc * 64 + n * 16 + (lane & 15);
        bf[n] = *(const half8*)((const char*)Bs + r * 128 +
                                (((kk * 4 + (lane >> 4)) ^ (r & 7)) << 4));
      }
#pragma unroll
      for (int m = 0; m < 4; m++)
#pragma unroll
        for (int n = 0; n < 4; n++)
          acc[m][n] = __builtin_amdgcn_mfma_f32_16x16x32_f16(af[m], bf[n], acc[m][n], 0, 0, 0);
    }
    __syncthreads();
  }
#pragma unroll
  for (int n = 0; n < 4; n++) {
    int col = ntile * 128 + wc * 64 + n * 16 + (lane & 15);
    float bs = bsum[col];
#pragma unroll
    for (int m = 0; m < 4; m++)
#pragma unroll
      for (int q = 0; q < 4; q++) {
        int row = mtile * 128 + wr * 64 + m * 16 + (lane >> 4) * 4 + q;  // = b*512 + t
        int bb = row >> 9, tt = row & 511;
        C[((size_t)tt * 64 + bb) * 4096 + col] = (_Float16)(acc[m][n][q] + bs);
      }
  }
}

// ---------------- phase 2: recurrence ----------------
// 128 WGs x 512 thr. WG: g = (bid&7)>>1, s32 = (bid&1)*16 + (bid>>3) (32 units).
// Wave w (0..7): gate G = w>>1, half uh = w&1 -> W_hh rows 1024*G + s32*32 + uh*16 ..
// Exchange (R6): hbuf u32[2][64][1024] ping-pong of tagged words ((t+1)<<16|h16).
// Consumer polls buf[t&1] until all tags==t; pending-only rereads; gather IS poll.
__global__ __launch_bounds__(512, 2) void k_lstm_rec(
    const _Float16* __restrict__ Whh,     // [4096][1024] f16
    const _Float16* __restrict__ xprojT,  // [512][64][4096] f16 time-major
    const int* __restrict__ seqlen,       // [64]
    unsigned* __restrict__ hbuf,          // [2][64][1024] tagged u32, zeroed per launch
    float* __restrict__ out) {            // [64][1024] f32
  __shared__ _Float16 h_lds[16 * 1024];  // 32 KB packed f16, XOR-swizzled 16B slots
  __shared__ float gates[128 * 17];      // transposed [col][row], pad 17

  const int bid = blockIdx.x;
  const int g = (bid & 7) >> 1;                 // batch group 0..3 (XCD-paired)
  const int s32 = (bid & 1) * 16 + (bid >> 3);  // unit slice 0..31 (32 units each)
  const int tid = threadIdx.x;
  const int wave = tid >> 6, lane = tid & 63;
  const int G = wave >> 1, uh = wave & 1;

  for (int i = tid; i < 4096; i += 512) ((uint64_t*)h_lds)[i] = 0ull;  // h_0 = 0

  // W_hh B-fragments, register-resident (8-wave mapping validated in R7)
  half8 wfrag[32];
  {
    const _Float16* wp = Whh +
        (size_t)(1024 * G + s32 * 32 + uh * 16 + (lane & 15)) * 1024 + (lane >> 4) * 8;
#pragma unroll
    for (int kk = 0; kk < 32; kk++) wfrag[kk] = *(const half8*)(wp + kk * 32);
  }

  int Lg = 1;
  for (int b = 0; b < 16; b++) {
    int L = seqlen[g * 16 + b];
    Lg = L > Lg ? L : Lg;
  }
  const int be = tid >> 5, ue = tid & 31;  // elementwise cell (batch row, unit-in-slice)
  const int mylen = seqlen[g * 16 + be];
  float c_state = 0.f;

  const int rowbase = (lane & 15) * 2048;   // A-frag row byte base
  const int xorm = ((lane & 15) & 7) << 4;  // A-frag XOR swizzle

  __syncthreads();  // h_lds zeros visible for t=0

  for (int t = 0; t < Lg; t++) {
    // xp loads (independent of h), issued before the poll-gather
    float xp[4];
#pragma unroll
    for (int q = 0; q < 4; q++) {
      int bm = (lane >> 4) * 4 + q;
      xp[q] = (float)xprojT[((size_t)t * 64 + g * 16 + bm) * 4096 + 1024 * G + s32 * 32 +
                            uh * 16 + (lane & 15)];
    }

    if (t > 0) {
      // poll-gather: 8 chunks/thread over [16][1024] tagged u32 (64KB/WG),
      // chunk ch = tid + i*512; single loop, pending-only re-read (R6 pattern).
      const unsigned* src = hbuf + ((size_t)(t & 1)) * 65536 + (size_t)g * 16384;
      const unsigned Etag = (unsigned)t << 16;
      u32x4 hv[8];
#pragma unroll
      for (int i = 0; i < 8; i++) {
        asm volatile("global_load_dwordx4 %0, %1, off sc0 sc1"
                     : "=v"(hv[i]) : "v"(src + (size_t)(tid + (i << 9)) * 4) : "memory");
      }
      asm volatile("s_waitcnt vmcnt(0)" ::: "memory");
      unsigned done = 0;
      for (;;) {
#pragma unroll
        for (int i = 0; i < 8; i++) {
          if (!(done & (1u << i))) {
            unsigned m = ((hv[i].x ^ Etag) | (hv[i].y ^ Etag) | (hv[i].z ^ Etag) |
                          (hv[i].w ^ Etag)) & 0xFFFF0000u;
            if (__all(m == 0u)) done |= 1u << i;
          }
        }
        if (done == 0xFFu) break;
#pragma unroll
        for (int i = 0; i < 8; i++) {
          if (!(done & (1u << i))) {
            asm volatile("global_load_dwordx4 %0, %1, off sc0 sc1"
                         : "=v"(hv[i]) : "v"(src + (size_t)(tid + (i << 9)) * 4) : "memory");
          }
        }
        asm volatile("s_waitcnt vmcnt(0)" ::: "memory");
      }
      // strip tags, pack 4 u32 -> 8B f16, write swizzled LDS (R6 map)
#pragma unroll
      for (int i = 0; i < 8; i++) {
        int ch = tid + (i << 9);
        int br = ch >> 8, cidx = ch & 255;
        unsigned lo = (hv[i].x & 0xFFFFu) | (hv[i].y << 16);
        unsigned hi = (hv[i].z & 0xFFFFu) | (hv[i].w << 16);
        *(uint64_t*)((char*)h_lds + br * 2048 + (((cidx >> 1) ^ (br & 7)) << 4) +
                     (cidx & 1) * 8) = (uint64_t)lo | ((uint64_t)hi << 32);
      }
    }
    __syncthreads();  // (A) h_lds ready; also WAR-protects gates

    // gates: M=16 x N=16/wave, K=1024 -> 32 MFMAs in 4 accumulator chains
    f32x4 a0 = (f32x4){0.f, 0.f, 0.f, 0.f};
    f32x4 a1 = (f32x4){0.f, 0.f, 0.f, 0.f};
    f32x4 a2 = (f32x4){0.f, 0.f, 0.f, 0.f};
    f32x4 a3 = (f32x4){0.f, 0.f, 0.f, 0.f};
    const char* lb = (const char*)h_lds + rowbase;
#pragma unroll
    for (int kk = 0; kk < 32; kk += 4) {
      half8 f0 = *(const half8*)(lb + ((((kk + 0) * 4 + (lane >> 4)) << 4) ^ xorm));
      half8 f1 = *(const half8*)(lb + ((((kk + 1) * 4 + (lane >> 4)) << 4) ^ xorm));
      half8 f2 = *(const half8*)(lb + ((((kk + 2) * 4 + (lane >> 4)) << 4) ^ xorm));
      half8 f3 = *(const half8*)(lb + ((((kk + 3) * 4 + (lane >> 4)) << 4) ^ xorm));
      a0 = __builtin_amdgcn_mfma_f32_16x16x32_f16(f0, wfrag[kk + 0], a0, 0, 0, 0);
      a1 = __builtin_amdgcn_mfma_f32_16x16x32_f16(f1, wfrag[kk + 1], a1, 0, 0, 0);
      a2 = __builtin_amdgcn_mfma_f32_16x16x32_f16(f2, wfrag[kk + 2], a2, 0, 0, 0);
      a3 = __builtin_amdgcn_mfma_f32_16x16x32_f16(f3, wfrag[kk + 3], a3, 0, 0, 0);
    }
    {
      f32x4 gv4;
#pragma unroll
      for (int q = 0; q < 4; q++) gv4[q] = (a0[q] + a1[q]) + (a2[q] + a3[q]) + xp[q];
      // col = gate*32 + unit_local (unit_local = uh*16 + (lane&15))
      *(f32x4*)&gates[(G * 32 + uh * 16 + (lane & 15)) * 17 + (lane >> 4) * 4] = gv4;
    }
    __syncthreads();  // (B) gates ready

    // elementwise: thread owns (be, ue)
    float iv = gates[(0 + ue) * 17 + be];
    float fv = gates[(32 + ue) * 17 + be];
    float gv = gates[(64 + ue) * 17 + be];
    float ov = gates[(96 + ue) * 17 + be];
    iv = 1.f / (1.f + __expf(-iv));
    fv = 1.f / (1.f + __expf(-fv));
    gv = 1.f - 2.f / (1.f + __expf(2.f * gv));
    ov = 1.f / (1.f + __expf(-ov));
    c_state = fv * c_state + iv * gv;
    float tc = 1.f - 2.f / (1.f + __expf(2.f * c_state));
    float hvv = ov * tc;
    if (t + 1 == mylen) out[(size_t)(g * 16 + be) * 1024 + s32 * 32 + ue] = hvv;

    if (t + 1 < Lg) {
      _Float16 hf16 = (_Float16)hvv;
      unsigned short hb;
      __builtin_memcpy(&hb, &hf16, 2);
      unsigned tw = ((unsigned)(t + 1) << 16) | (unsigned)hb;
      // 32 lanes x 4B = 128B contiguous per row; readiness travels with data
      __hip_atomic_store(hbuf + ((size_t)((t + 1) & 1)) * 65536 +
                             (size_t)(g * 16 + be) * 1024 + s32 * 32 + ue,
                         tw, __ATOMIC_RELAXED, __HIP_MEMORY_SCOPE_AGENT);
      // no drain, no flag, no barrier
    }
  }
}

// ---------------- launch ----------------
extern "C" void kernel_launch(void* const* d_in, const int* in_sizes, int n_in, void* d_out,
                              int out_size, void* d_ws, size_t ws_size, hipStream_t stream) {
  const float* emb = (const float*)d_in[0];   // [64,512,1024]
  const int* slen = (const int*)d_in[1];      // [64]
  const float* Wih = (const float*)d_in[2];   // [4096,1024]
  const float* Whh = (const float*)d_in[3];   // [4096,1024]
  const float* bih = (const float*)d_in[4];   // [4096]
  const float* bhh = (const float*)d_in[5];   // [4096]
  float* out = (float*)d_out;

  char* ws = (char*)d_ws;
  _Float16* xprojT = (_Float16*)(ws + 0);        // 268,435,456 B [512][64][4096]
  _Float16* xf = (_Float16*)(ws + 268435456);    //  67,108,864 B (dead after GEMM)
  unsigned* hbuf = (unsigned*)(ws + 268435456);  //     524,288 B [2][64][1024] u32 (aliases xf)
  _Float16* wihf = (_Float16*)(ws + 335544320);  //   8,388,608 B
  _Float16* whhf = (_Float16*)(ws + 343932928);  //   8,388,608 B
  float* bsum = (float*)(ws + 352321536);        //      16,384 B
  // total ws use: 352,337,920 B

  k_f32_to_f16<<<(8388608 + 255) / 256, 256, 0, stream>>>(emb, xf, 8388608);
  k_f32_to_f16<<<(1048576 + 255) / 256, 256, 0, stream>>>(Wih, wihf, 1048576);
  k_f32_to_f16<<<(1048576 + 255) / 256, 256, 0, stream>>>(Whh, whhf, 1048576);
  k_bias_sum<<<16, 256, 0, stream>>>(bih, bhh, bsum);
  k_gemm_xproj<<<8192, 256, 0, stream>>>(xf, wihf, bsum, xprojT);
  // zero ALL tags AFTER the GEMM consumed xf (hbuf aliases xf); tag 0 never polled
  hipMemsetAsync(hbuf, 0, 524288, stream);
  k_lstm_rec<<<128, 512, 0, stream>>>(whhf, xprojT, slen, hbuf, out);
}

// Round 10
// 2161.026 us; speedup vs baseline: 1.5898x; 1.4315x over previous
//
#include <hip/hip_runtime.h>
#include <stdint.h>

// UniLSTM: B=64, T=512, E=1024, H=1024.
// Phase 0: f32->f16 converts + bias sum.
// Phase 1: xprojT[T][64][4096] = (x @ W_ih^T + bsum), f16, time-major.
// Phase 2: persistent recurrence, 256 WGs x 256 thr = 4 groups x 64 unit-slices.
//   R10 = R6 exactly, except the exchange words are f16 with a 1-bit step
//   parity stolen from the LSB (ping-pong => adjacent tenants of a slot differ
//   by one generation => 1 bit suffices). Halves the bypass gather bytes
//   (64->32 KB/WG/step) and the h-store bytes; deletes the repack. Init
//   collision handled by per-buffer memset patterns (0x01 / 0x00).

typedef _Float16 half8 __attribute__((ext_vector_type(8)));
typedef _Float16 half4_ __attribute__((ext_vector_type(4)));
typedef float f32x4 __attribute__((ext_vector_type(4)));
typedef unsigned int u32x4 __attribute__((ext_vector_type(4)));

// ---------------- converts ----------------
__global__ void k_f32_to_f16(const float* __restrict__ s, _Float16* __restrict__ d, int n4) {
  int i = blockIdx.x * blockDim.x + threadIdx.x;
  if (i >= n4) return;
  f32x4 v = ((const f32x4*)s)[i];
  half4_ h;
  h.x = (_Float16)v.x; h.y = (_Float16)v.y; h.z = (_Float16)v.z; h.w = (_Float16)v.w;
  ((half4_*)d)[i] = h;
}

__global__ void k_bias_sum(const float* __restrict__ a, const float* __restrict__ b,
                           float* __restrict__ o) {
  int i = blockIdx.x * blockDim.x + threadIdx.x;
  if (i < 4096) o[i] = a[i] + b[i];
}

// ---------------- phase 1: input projection GEMM ----------------
// logical C[M=32768, N=4096] = X[M,1024] @ W[N,1024]^T + bsum[N], stored TIME-MAJOR:
// row = b*512+t -> written at C[(t*64 + b)*4096 + col]
__global__ __launch_bounds__(256, 2) void k_gemm_xproj(
    const _Float16* __restrict__ X, const _Float16* __restrict__ W,
    const float* __restrict__ bsum, _Float16* __restrict__ C) {
  __shared__ _Float16 As[128 * 64];
  __shared__ _Float16 Bs[128 * 64];
  const int bid = blockIdx.x;
  const int ntile = bid & 31, mtile = bid >> 5;
  const int tid = threadIdx.x;
  const int wave = tid >> 6, lane = tid & 63;
  const int wr = wave >> 1, wc = wave & 1;
  const int R0 = lane >> 3, cg = lane & 7;

  f32x4 acc[4][4];
#pragma unroll
  for (int m = 0; m < 4; m++)
#pragma unroll
    for (int n = 0; n < 4; n++) acc[m][n] = (f32x4){0.f, 0.f, 0.f, 0.f};

  for (int k0 = 0; k0 < 1024; k0 += 64) {
#pragma unroll
    for (int i = 0; i < 4; i++) {
      const int rr = (wave * 4 + i) * 8 + R0;
      const _Float16* ga = X + (size_t)(mtile * 128 + rr) * 1024 + k0 + ((cg ^ (rr & 7)) * 8);
      const _Float16* gb = W + (size_t)(ntile * 128 + rr) * 1024 + k0 + ((cg ^ (rr & 7)) * 8);
      __builtin_amdgcn_global_load_lds(
          (const __attribute__((address_space(1))) void*)ga,
          (__attribute__((address_space(3))) void*)((char*)As + (wave * 4 + i) * 1024), 16, 0, 0);
      __builtin_amdgcn_global_load_lds(
          (const __attribute__((address_space(1))) void*)gb,
          (__attribute__((address_space(3))) void*)((char*)Bs + (wave * 4 + i) * 1024), 16, 0, 0);
    }
    asm volatile("s_waitcnt vmcnt(0)" ::: "memory");
    __syncthreads();
#pragma unroll
    for (int kk = 0; kk < 2; kk++) {
      half8 af[4], bf[4];
#pragma unroll
      for (int m = 0; m < 4; m++) {
        int r = wr * 64 + m * 16 + (lane & 15);
        af[m] = *(const half8*)((const char*)As + r * 128 +
                                (((kk * 4 + (lane >> 4)) ^ (r & 7)) << 4));
      }
#pragma unroll
      for (int n = 0; n < 4; n++) {
        int r = wc * 64 + n * 16 + (lane & 15);
        bf[n] = *(const half8*)((const char*)Bs + r * 128 +
                                (((kk * 4 + (lane >> 4)) ^ (r & 7)) << 4));
      }
#pragma unroll
      for (int m = 0; m < 4; m++)
#pragma unroll
        for (int n = 0; n < 4; n++)
          acc[m][n] = __builtin_amdgcn_mfma_f32_16x16x32_f16(af[m], bf[n], acc[m][n], 0, 0, 0);
    }
    __syncthreads();
  }
#pragma unroll
  for (int n = 0; n < 4; n++) {
    int col = ntile * 128 + wc * 64 + n * 16 + (lane & 15);
    float bs = bsum[col];
#pragma unroll
    for (int m = 0; m < 4; m++)
#pragma unroll
      for (int q = 0; q < 4; q++) {
        int row = mtile * 128 + wr * 64 + m * 16 + (lane >> 4) * 4 + q;  // = b*512 + t
        int bb = row >> 9, tt = row & 511;
        C[((size_t)tt * 64 + bb) * 4096 + col] = (_Float16)(acc[m][n][q] + bs);
      }
  }
}

// ---------------- phase 2: recurrence ----------------
// WG (g, s): XCD-swizzled: g=(bid&7)>>1, s=(bid&1)*32+(bid>>3).
// Wave w = gate w; MFMA col n = unit s*16+n -> W_hh row 1024*w + s*16 + n.
// Exchange: hbuf u16[2][64][1024] ping-pong of f16 words whose LSB is the step
// parity ptag(t)=((t>>1)&1)^1. Gather IS the poll; pending-only rereads.
__global__ __launch_bounds__(256, 1) void k_lstm_rec(
    const _Float16* __restrict__ Whh,      // [4096][1024] f16
    const _Float16* __restrict__ xprojT,   // [512][64][4096] f16 time-major
    const int* __restrict__ seqlen,        // [64]
    unsigned short* __restrict__ hbuf,     // [2][64][1024] f16+parity, init 0x01/0x00
    float* __restrict__ out) {             // [64][1024] f32
  __shared__ _Float16 h_lds[16 * 1024];  // 32 KB packed f16, XOR-swizzled 16B slots
  __shared__ float gates[64 * 17];       // transposed [col][row], pad 17

  const int bid = blockIdx.x;
  const int x8 = bid & 7;                    // XCD (perf heuristic only)
  const int g = x8 >> 1;                     // batch group 0..3
  const int s = (x8 & 1) * 32 + (bid >> 3);  // unit slice 0..63
  const int tid = threadIdx.x;
  const int wave = tid >> 6, lane = tid & 63;

  for (int i = tid; i < 4096; i += 256) ((uint64_t*)h_lds)[i] = 0ull;  // h_0 = 0

  // W_hh B-fragments, register-resident (mapping validated R2/R5/R6)
  half8 wfrag[32];
  {
    const _Float16* wp =
        Whh + (size_t)(1024 * wave + s * 16 + (lane & 15)) * 1024 + (lane >> 4) * 8;
#pragma unroll
    for (int kk = 0; kk < 32; kk++) wfrag[kk] = *(const half8*)(wp + kk * 32);
  }

  int Lg = 1;
  for (int b = 0; b < 16; b++) {
    int L = seqlen[g * 16 + b];
    Lg = L > Lg ? L : Lg;
  }
  const int be = tid >> 4, ue = tid & 15;  // elementwise cell (batch row, unit)
  const int mylen = seqlen[g * 16 + be];
  float c_state = 0.f;

  const int rowbase = (lane & 15) * 2048;   // A-frag row byte base
  const int xorm = ((lane & 15) & 7) << 4;  // A-frag XOR swizzle

  __syncthreads();  // h_lds zeros visible for t=0

  for (int t = 0; t < Lg; t++) {
    // xp loads (independent of h), issued before the poll-gather
    float xp[4];
#pragma unroll
    for (int q = 0; q < 4; q++) {
      int bm = (lane >> 4) * 4 + q;
      xp[q] = (float)xprojT[((size_t)t * 64 + g * 16 + bm) * 4096 + 1024 * wave + s * 16 +
                            (lane & 15)];
    }

    if (t > 0) {
      // poll-gather: 8 chunks/thread over [16][1024] f16 (32KB/WG), 16B chunks.
      // parity for step t: ptag = ((t>>1)&1)^1, at bit 0 of each u16.
      const unsigned short* src = hbuf + ((size_t)(t & 1)) * 65536 + (size_t)g * 16384;
      const unsigned pb = (((unsigned)t >> 1) & 1u) ^ 1u;
      const unsigned exp2 = pb ? 0x00010001u : 0u;
      u32x4 hv[8];
#pragma unroll
      for (int i = 0; i < 8; i++) {
        asm volatile("global_load_dwordx4 %0, %1, off sc0 sc1"
                     : "=v"(hv[i]) : "v"(src + (size_t)(tid + (i << 8)) * 8) : "memory");
      }
      asm volatile("s_waitcnt vmcnt(0)" ::: "memory");
      unsigned done = 0;
      for (;;) {
#pragma unroll
        for (int i = 0; i < 8; i++) {
          if (!(done & (1u << i))) {
            unsigned m = ((hv[i].x ^ exp2) | (hv[i].y ^ exp2) | (hv[i].z ^ exp2) |
                          (hv[i].w ^ exp2)) & 0x00010001u;
            if (__all(m == 0u)) done |= 1u << i;
          }
        }
        if (done == 0xFFu) break;
#pragma unroll
        for (int i = 0; i < 8; i++) {
          if (!(done & (1u << i))) {
            asm volatile("global_load_dwordx4 %0, %1, off sc0 sc1"
                         : "=v"(hv[i]) : "v"(src + (size_t)(tid + (i << 8)) * 8) : "memory");
          }
        }
        asm volatile("s_waitcnt vmcnt(0)" ::: "memory");
      }
      // chunks are final f16 payload (parity noise <= 1 ulp) -> straight to LDS
#pragma unroll
      for (int i = 0; i < 8; i++) {
        int ch = tid + (i << 8);          // 0..2047
        int br = ch >> 7, cidx = ch & 127;
        *(u32x4*)((char*)h_lds + br * 2048 + ((cidx ^ (br & 7)) << 4)) = hv[i];
      }
    }
    __syncthreads();  // (A) h_lds ready; also WAR-protects gates

    // gates: M=16 x N=16, K=1024 -> 32 MFMAs in 4 accumulator chains
    f32x4 a0 = (f32x4){0.f, 0.f, 0.f, 0.f};
    f32x4 a1 = (f32x4){0.f, 0.f, 0.f, 0.f};
    f32x4 a2 = (f32x4){0.f, 0.f, 0.f, 0.f};
    f32x4 a3 = (f32x4){0.f, 0.f, 0.f, 0.f};
    const char* lb = (const char*)h_lds + rowbase;
#pragma unroll
    for (int kk = 0; kk < 32; kk += 4) {
      half8 f0 = *(const half8*)(lb + ((((kk + 0) * 4 + (lane >> 4)) << 4) ^ xorm));
      half8 f1 = *(const half8*)(lb + ((((kk + 1) * 4 + (lane >> 4)) << 4) ^ xorm));
      half8 f2 = *(const half8*)(lb + ((((kk + 2) * 4 + (lane >> 4)) << 4) ^ xorm));
      half8 f3 = *(const half8*)(lb + ((((kk + 3) * 4 + (lane >> 4)) << 4) ^ xorm));
      a0 = __builtin_amdgcn_mfma_f32_16x16x32_f16(f0, wfrag[kk + 0], a0, 0, 0, 0);
      a1 = __builtin_amdgcn_mfma_f32_16x16x32_f16(f1, wfrag[kk + 1], a1, 0, 0, 0);
      a2 = __builtin_amdgcn_mfma_f32_16x16x32_f16(f2, wfrag[kk + 2], a2, 0, 0, 0);
      a3 = __builtin_amdgcn_mfma_f32_16x16x32_f16(f3, wfrag[kk + 3], a3, 0, 0, 0);
    }
    {
      f32x4 gv4;
#pragma unroll
      for (int q = 0; q < 4; q++) gv4[q] = (a0[q] + a1[q]) + (a2[q] + a3[q]) + xp[q];
      *(f32x4*)&gates[(wave * 16 + (lane & 15)) * 17 + (lane >> 4) * 4] = gv4;
    }
    __syncthreads();  // (B) gates ready

    // elementwise: thread owns (be, ue)
    float iv = gates[(0 + ue) * 17 + be];
    float fv = gates[(16 + ue) * 17 + be];
    float gv = gates[(32 + ue) * 17 + be];
    float ov = gates[(48 + ue) * 17 + be];
    iv = 1.f / (1.f + __expf(-iv));
    fv = 1.f / (1.f + __expf(-fv));
    gv = 1.f - 2.f / (1.f + __expf(2.f * gv));
    ov = 1.f / (1.f + __expf(-ov));
    c_state = fv * c_state + iv * gv;
    float tc = 1.f - 2.f / (1.f + __expf(2.f * c_state));
    float hv = ov * tc;
    if (t + 1 == mylen) out[(size_t)(g * 16 + be) * 1024 + s * 16 + ue] = hv;

    if (t + 1 < Lg) {
      _Float16 hf = (_Float16)hv;
      unsigned short hb;
      __builtin_memcpy(&hb, &hf, 2);
      unsigned ps = (((unsigned)(t + 1) >> 1) & 1u) ^ 1u;
      hb = (unsigned short)((hb & 0xFFFEu) | ps);  // steal LSB for parity
      __hip_atomic_store(hbuf + ((size_t)((t + 1) & 1)) * 65536 +
                             (size_t)(g * 16 + be) * 1024 + s * 16 + ue,
                         hb, __ATOMIC_RELAXED, __HIP_MEMORY_SCOPE_AGENT);
      // no drain, no flag, no barrier — parity travels with the data
    }
  }
}

// ---------------- launch ----------------
extern "C" void kernel_launch(void* const* d_in, const int* in_sizes, int n_in, void* d_out,
                              int out_size, void* d_ws, size_t ws_size, hipStream_t stream) {
  const float* emb = (const float*)d_in[0];   // [64,512,1024]
  const int* slen = (const int*)d_in[1];      // [64]
  const float* Wih = (const float*)d_in[2];   // [4096,1024]
  const float* Whh = (const float*)d_in[3];   // [4096,1024]
  const float* bih = (const float*)d_in[4];   // [4096]
  const float* bhh = (const float*)d_in[5];   // [4096]
  float* out = (float*)d_out;

  char* ws = (char*)d_ws;
  _Float16* xprojT = (_Float16*)(ws + 0);        // 268,435,456 B [512][64][4096]
  _Float16* xf = (_Float16*)(ws + 268435456);    //  67,108,864 B (dead after GEMM)
  unsigned short* hbuf =
      (unsigned short*)(ws + 268435456);         //     262,144 B [2][64][1024] u16 (aliases xf)
  _Float16* wihf = (_Float16*)(ws + 335544320);  //   8,388,608 B
  _Float16* whhf = (_Float16*)(ws + 343932928);  //   8,388,608 B
  float* bsum = (float*)(ws + 352321536);        //      16,384 B
  // total ws use: 352,337,920 B

  k_f32_to_f16<<<(8388608 + 255) / 256, 256, 0, stream>>>(emb, xf, 8388608);
  k_f32_to_f16<<<(1048576 + 255) / 256, 256, 0, stream>>>(Wih, wihf, 1048576);
  k_f32_to_f16<<<(1048576 + 255) / 256, 256, 0, stream>>>(Whh, whhf, 1048576);
  k_bias_sum<<<16, 256, 0, stream>>>(bih, bhh, bsum);
  k_gemm_xproj<<<8192, 256, 0, stream>>>(xf, wihf, bsum, xprojT);
  // init parity AFTER the GEMM consumed xf (hbuf aliases xf):
  // buffer0 (even t) LSB=1 (h_2 expects 0), buffer1 (odd t) LSB=0 (h_1 expects 1)
  hipMemsetAsync((char*)hbuf, 0x01, 131072, stream);
  hipMemsetAsync((char*)hbuf + 131072, 0x00, 131072, stream);
  k_lstm_rec<<<256, 256, 0, stream>>>(whhf, xprojT, slen, hbuf, out);
}

// Round 11
// 2098.163 us; speedup vs baseline: 1.6375x; 1.0300x over previous
//
#include <hip/hip_runtime.h>
#include <stdint.h>

// UniLSTM: B=64, T=512, E=1024, H=1024.
// R11: the x_proj GEMM is FUSED into the recurrence. Each WG computes, in its
// poll-wait slack, the xp tile (16 rows x its 64 gate-cols) for step t+1 from
// an LDS-staged xf A-tile and register-resident W_ih fragments. Deletes the
// serial 230us GEMM phase and the 268MB xprojT buffer (write + re-read).
// Exchange = R6's tagged u32 ping-pong verbatim (proven optimal R7/R9/R10:
// chain-latency bound, every traffic perturbation regressed).
//
// Phase 0: f32->f16 converts (emb->xf, Wih, Whh) + bias sum.
// Phase 1: persistent recurrence, 256 WGs x 256 thr = 4 groups x 64 unit-slices.

typedef _Float16 half8 __attribute__((ext_vector_type(8)));
typedef _Float16 half4_ __attribute__((ext_vector_type(4)));
typedef float f32x4 __attribute__((ext_vector_type(4)));
typedef unsigned int u32x4 __attribute__((ext_vector_type(4)));

// ---------------- converts ----------------
__global__ void k_f32_to_f16(const float* __restrict__ s, _Float16* __restrict__ d, int n4) {
  int i = blockIdx.x * blockDim.x + threadIdx.x;
  if (i >= n4) return;
  f32x4 v = ((const f32x4*)s)[i];
  half4_ h;
  h.x = (_Float16)v.x; h.y = (_Float16)v.y; h.z = (_Float16)v.z; h.w = (_Float16)v.w;
  ((half4_*)d)[i] = h;
}

__global__ void k_bias_sum(const float* __restrict__ a, const float* __restrict__ b,
                           float* __restrict__ o) {
  int i = blockIdx.x * blockDim.x + threadIdx.x;
  if (i < 4096) o[i] = a[i] + b[i];
}

// ---------------- fused recurrence ----------------
// WG (g, s): XCD-swizzled: g=(bid&7)>>1, s=(bid&1)*32+(bid>>3).
// Wave w = gate w; MFMA col n = unit s*16+n -> W_{hh,ih} row 1024*w + s*16 + n.
// Exchange: hbuf u32[2][64][1024] ping-pong of ((t+1)<<16|h16) (R6 verbatim).
// Per step: [stage xf A(t+1)] [poll+gather h(t)] (A) [hh-MFMA seeded with xa]
// (B) [elementwise, h-store] [xa(t+1) = xf(t+1) @ Wih + bsum, in-register].
__global__ __launch_bounds__(256, 1) void k_lstm_rec(
    const _Float16* __restrict__ Whh,   // [4096][1024] f16
    const _Float16* __restrict__ Wih,   // [4096][1024] f16
    const _Float16* __restrict__ xf,    // [64][512][1024] f16 (emb converted)
    const float* __restrict__ bsum,     // [4096] b_ih+b_hh
    const int* __restrict__ seqlen,     // [64]
    unsigned* __restrict__ hbuf,        // [2][64][1024] tagged u32, zeroed per launch
    float* __restrict__ out) {          // [64][1024] f32
  __shared__ _Float16 h_lds[16 * 1024];    // 32 KB, XOR-swizzled 16B slots
  __shared__ _Float16 axf[2][16 * 1024];   // 2 x 32 KB xf A-tiles, same swizzle
  __shared__ float gates[64 * 17];         // transposed [col][row], pad 17

  const int bid = blockIdx.x;
  const int x8 = bid & 7;                    // XCD (perf heuristic only)
  const int g = x8 >> 1;                     // batch group 0..3
  const int s = (x8 & 1) * 32 + (bid >> 3);  // unit slice 0..63
  const int tid = threadIdx.x;
  const int wave = tid >> 6, lane = tid & 63;

  for (int i = tid; i < 4096; i += 256) ((uint64_t*)h_lds)[i] = 0ull;  // h_0 = 0

  // W_hh and W_ih B-fragments, register-resident (mapping validated R2..R10)
  half8 wfhh[32], wfih[32];
  {
    const size_t roff = (size_t)(1024 * wave + s * 16 + (lane & 15)) * 1024 + (lane >> 4) * 8;
    const _Float16* ph = Whh + roff;
    const _Float16* pi = Wih + roff;
#pragma unroll
    for (int kk = 0; kk < 32; kk++) {
      wfhh[kk] = *(const half8*)(ph + kk * 32);
      wfih[kk] = *(const half8*)(pi + kk * 32);
    }
  }
  const float bs = bsum[1024 * wave + s * 16 + (lane & 15)];

  int Lg = 1;
  for (int b = 0; b < 16; b++) {
    int L = seqlen[g * 16 + b];
    Lg = L > Lg ? L : Lg;
  }
  const int be = tid >> 4, ue = tid & 15;  // elementwise cell (batch row, unit)
  const int mylen = seqlen[g * 16 + be];
  float c_state = 0.f;

  const int rowbase = (lane & 15) * 2048;   // A-frag row byte base
  const int xorm = ((lane & 15) & 7) << 4;  // A-frag XOR swizzle

  // stage xf A-tile for time tt into axf[tt&1]: 2048 16B chunks, linear LDS
  // dest + pre-swizzled global source (rule #21). br = chunk>>7, cidx = chunk&127.
  auto STAGE = [&](int tt) {
    const int bufsel = tt & 1;
#pragma unroll
    for (int i = 0; i < 8; i++) {
      const int ch = tid + (i << 8);
      const int br = ch >> 7, cidx = ch & 127;
      const _Float16* gp =
          xf + ((size_t)(g * 16 + br) * 512 + tt) * 1024 + ((cidx ^ (br & 7)) * 8);
      __builtin_amdgcn_global_load_lds(
          (const __attribute__((address_space(1))) void*)gp,
          (__attribute__((address_space(3))) void*)((char*)axf[bufsel] +
                                                    ((wave * 64 + (i << 8)) << 4)),
          16, 0, 0);
    }
  };

  // in-register xp accumulators, carried across the loop (bias seeded in xa0)
  f32x4 xa0, xa1, xa2, xa3;
  auto XP_COMPUTE = [&](int tt) {
    xa0 = (f32x4){bs, bs, bs, bs};
    xa1 = (f32x4){0.f, 0.f, 0.f, 0.f};
    xa2 = (f32x4){0.f, 0.f, 0.f, 0.f};
    xa3 = (f32x4){0.f, 0.f, 0.f, 0.f};
    const char* ab = (const char*)axf[tt & 1] + rowbase;
#pragma unroll
    for (int kk = 0; kk < 32; kk += 4) {
      half8 f0 = *(const half8*)(ab + ((((kk + 0) * 4 + (lane >> 4)) << 4) ^ xorm));
      half8 f1 = *(const half8*)(ab + ((((kk + 1) * 4 + (lane >> 4)) << 4) ^ xorm));
      half8 f2 = *(const half8*)(ab + ((((kk + 2) * 4 + (lane >> 4)) << 4) ^ xorm));
      half8 f3 = *(const half8*)(ab + ((((kk + 3) * 4 + (lane >> 4)) << 4) ^ xorm));
      xa0 = __builtin_amdgcn_mfma_f32_16x16x32_f16(f0, wfih[kk + 0], xa0, 0, 0, 0);
      xa1 = __builtin_amdgcn_mfma_f32_16x16x32_f16(f1, wfih[kk + 1], xa1, 0, 0, 0);
      xa2 = __builtin_amdgcn_mfma_f32_16x16x32_f16(f2, wfih[kk + 2], xa2, 0, 0, 0);
      xa3 = __builtin_amdgcn_mfma_f32_16x16x32_f16(f3, wfih[kk + 3], xa3, 0, 0, 0);
    }
  };

  // prologue: stage A(0), drain, barrier, compute xa(0)
  STAGE(0);
  asm volatile("s_waitcnt vmcnt(0)" ::: "memory");
  __syncthreads();
  XP_COMPUTE(0);

  for (int t = 0; t < Lg; t++) {
    if (t + 1 < Lg) STAGE(t + 1);  // issue next A-tile; drained by poll/barrier A

    if (t > 0) {
      // R6 poll-gather verbatim: 16 chunks/thread over [16][1024] tagged u32,
      // two halves of 8, pending-only rereads; gather IS the poll.
      const unsigned* src = hbuf + ((size_t)(t & 1)) * 65536 + (size_t)g * 16384;
      const unsigned Etag = (unsigned)t << 16;
#pragma unroll
      for (int hf = 0; hf < 2; hf++) {
        u32x4 hv[8];
        unsigned done = 0;
        while (done != 0xFFu) {
#pragma unroll
          for (int i = 0; i < 8; i++) {
            if (!(done & (1u << i))) {
              asm volatile("global_load_dwordx4 %0, %1, off sc0 sc1"
                           : "=v"(hv[i])
                           : "v"(src + (size_t)(tid + ((hf * 8 + i) << 8)) * 4)
                           : "memory");
            }
          }
          asm volatile("s_waitcnt vmcnt(0)" ::: "memory");
#pragma unroll
          for (int i = 0; i < 8; i++) {
            if (!(done & (1u << i))) {
              unsigned m = ((hv[i].x ^ Etag) | (hv[i].y ^ Etag) | (hv[i].z ^ Etag) |
                            (hv[i].w ^ Etag)) & 0xFFFF0000u;
              if (__all(m == 0u)) done |= 1u << i;
            }
          }
        }
#pragma unroll
        for (int i = 0; i < 8; i++) {
          int ch = tid + ((hf * 8 + i) << 8);
          int br = ch >> 8, cidx = ch & 255;
          unsigned lo = (hv[i].x & 0xFFFFu) | (hv[i].y << 16);
          unsigned hi = (hv[i].z & 0xFFFFu) | (hv[i].w << 16);
          *(uint64_t*)((char*)h_lds + br * 2048 + (((cidx >> 1) ^ (br & 7)) << 4) +
                       (cidx & 1) * 8) = (uint64_t)lo | ((uint64_t)hi << 32);
        }
      }
    }
    __syncthreads();  // (A) h_lds + axf[(t+1)&1] ready; WAR-protects gates

    // gates: hh-MFMAs seeded with the xp accumulators (C-operand chaining)
    f32x4 a0 = xa0, a1 = xa1, a2 = xa2, a3 = xa3;
    const char* lb = (const char*)h_lds + rowbase;
#pragma unroll
    for (int kk = 0; kk < 32; kk += 4) {
      half8 f0 = *(const half8*)(lb + ((((kk + 0) * 4 + (lane >> 4)) << 4) ^ xorm));
      half8 f1 = *(const half8*)(lb + ((((kk + 1) * 4 + (lane >> 4)) << 4) ^ xorm));
      half8 f2 = *(const half8*)(lb + ((((kk + 2) * 4 + (lane >> 4)) << 4) ^ xorm));
      half8 f3 = *(const half8*)(lb + ((((kk + 3) * 4 + (lane >> 4)) << 4) ^ xorm));
      a0 = __builtin_amdgcn_mfma_f32_16x16x32_f16(f0, wfhh[kk + 0], a0, 0, 0, 0);
      a1 = __builtin_amdgcn_mfma_f32_16x16x32_f16(f1, wfhh[kk + 1], a1, 0, 0, 0);
      a2 = __builtin_amdgcn_mfma_f32_16x16x32_f16(f2, wfhh[kk + 2], a2, 0, 0, 0);
      a3 = __builtin_amdgcn_mfma_f32_16x16x32_f16(f3, wfhh[kk + 3], a3, 0, 0, 0);
    }
    {
      f32x4 gv4;
#pragma unroll
      for (int q = 0; q < 4; q++) gv4[q] = (a0[q] + a1[q]) + (a2[q] + a3[q]);
      *(f32x4*)&gates[(wave * 16 + (lane & 15)) * 17 + (lane >> 4) * 4] = gv4;
    }
    __syncthreads();  // (B) gates ready

    // elementwise: thread owns (be, ue)
    float iv = gates[(0 + ue) * 17 + be];
    float fv = gates[(16 + ue) * 17 + be];
    float gv = gates[(32 + ue) * 17 + be];
    float ov = gates[(48 + ue) * 17 + be];
    iv = 1.f / (1.f + __expf(-iv));
    fv = 1.f / (1.f + __expf(-fv));
    gv = 1.f - 2.f / (1.f + __expf(2.f * gv));
    ov = 1.f / (1.f + __expf(-ov));
    c_state = fv * c_state + iv * gv;
    float tc = 1.f - 2.f / (1.f + __expf(2.f * c_state));
    float hv = ov * tc;
    if (t + 1 == mylen) out[(size_t)(g * 16 + be) * 1024 + s * 16 + ue] = hv;

    if (t + 1 < Lg) {
      _Float16 hf16 = (_Float16)hv;
      unsigned short hb;
      __builtin_memcpy(&hb, &hf16, 2);
      unsigned tw = ((unsigned)(t + 1) << 16) | (unsigned)hb;
      __hip_atomic_store(hbuf + ((size_t)((t + 1) & 1)) * 65536 +
                             (size_t)(g * 16 + be) * 1024 + s * 16 + ue,
                         tw, __ATOMIC_RELAXED, __HIP_MEMORY_SCOPE_AGENT);
      // no drain, no flag — readiness travels with the data (R6)

      // xp(t+1): fills the poll-wait slack; shifts all WGs' polls equally,
      // improving first-poll hit rate. axf staged at step top, barrier'd at A.
      XP_COMPUTE(t + 1);
    }
  }
}

// ---------------- launch ----------------
extern "C" void kernel_launch(void* const* d_in, const int* in_sizes, int n_in, void* d_out,
                              int out_size, void* d_ws, size_t ws_size, hipStream_t stream) {
  const float* emb = (const float*)d_in[0];   // [64,512,1024]
  const int* slen = (const int*)d_in[1];      // [64]
  const float* Wih = (const float*)d_in[2];   // [4096,1024]
  const float* Whh = (const float*)d_in[3];   // [4096,1024]
  const float* bih = (const float*)d_in[4];   // [4096]
  const float* bhh = (const float*)d_in[5];   // [4096]
  float* out = (float*)d_out;

  char* ws = (char*)d_ws;
  _Float16* xf = (_Float16*)(ws + 0);           //  67,108,864 B [64][512][1024] f16
  _Float16* wihf = (_Float16*)(ws + 67108864);  //   8,388,608 B
  _Float16* whhf = (_Float16*)(ws + 75497472);  //   8,388,608 B
  float* bsum = (float*)(ws + 83886080);        //      16,384 B
  unsigned* hbuf = (unsigned*)(ws + 83902464);  //     524,288 B [2][64][1024] u32
  // total ws use: 84,426,752 B

  k_f32_to_f16<<<(8388608 + 255) / 256, 256, 0, stream>>>(emb, xf, 8388608);
  k_f32_to_f16<<<(1048576 + 255) / 256, 256, 0, stream>>>(Wih, wihf, 1048576);
  k_f32_to_f16<<<(1048576 + 255) / 256, 256, 0, stream>>>(Whh, whhf, 1048576);
  k_bias_sum<<<16, 256, 0, stream>>>(bih, bhh, bsum);
  hipMemsetAsync(hbuf, 0, 524288, stream);  // zero tags; tag 0 never polled
  k_lstm_rec<<<256, 256, 0, stream>>>(whhf, wihf, xf, bsum, slen, hbuf, out);
}